// Round 9
// baseline (562.369 us; speedup 1.0000x reference)
//
#include <hip/hip_runtime.h>
#include <stdint.h>

typedef __attribute__((ext_vector_type(8))) short short8;
typedef __attribute__((ext_vector_type(8))) unsigned short ushort8;
typedef __attribute__((ext_vector_type(4))) float f32x4;

__device__ __forceinline__ ushort f2bf(float f) {
  union { float f; uint32_t u; } v; v.f = f;
  uint32_t r = v.u + 0x7FFFu + ((v.u >> 16) & 1u);
  return (ushort)(r >> 16);
}

__device__ __forceinline__ float fexp2(float x) {  // 2^x, single v_exp_f32
  float r;
  asm("v_exp_f32 %0, %1" : "=v"(r) : "v"(x));
  return r;
}

__device__ __forceinline__ void gld16(const ushort* g, ushort* l) {
  __builtin_amdgcn_global_load_lds((const __attribute__((address_space(1))) void*)g,
                                   (__attribute__((address_space(3))) void*)l, 16, 0, 0);
}

// ---------------- fp32 -> bf16 elementwise ----------------
__global__ __launch_bounds__(256) void k_f32_to_bf16(const float* __restrict__ in,
                                                     ushort* __restrict__ out, long n) {
  long i = ((long)blockIdx.x * 256 + threadIdx.x) * 8;
  if (i >= n) return;
  float4 a = *(const float4*)(in + i);
  float4 b = *(const float4*)(in + i + 4);
  ushort8 o;
  o[0] = f2bf(a.x); o[1] = f2bf(a.y); o[2] = f2bf(a.z); o[3] = f2bf(a.w);
  o[4] = f2bf(b.x); o[5] = f2bf(b.y); o[6] = f2bf(b.z); o[7] = f2bf(b.w);
  *(ushort8*)(out + i) = o;
}

// ---------------- fp32 (R x C) -> bf16 transposed (C x R), out row-stride R ----------------
__global__ __launch_bounds__(256) void k_w_transpose(const float* __restrict__ in,
                                                     ushort* __restrict__ out, int R, int C) {
  __shared__ float t[32][33];
  int tx = threadIdx.x & 31, ty = threadIdx.x >> 5;
  int r0 = blockIdx.y * 32, c0 = blockIdx.x * 32;
#pragma unroll
  for (int i = 0; i < 4; i++)
    t[ty + i * 8][tx] = in[(size_t)(r0 + ty + i * 8) * C + c0 + tx];
  __syncthreads();
#pragma unroll
  for (int i = 0; i < 4; i++)
    out[(size_t)(c0 + ty + i * 8) * R + r0 + tx] = f2bf(t[tx][ty + i * 8]);
}

// ---------------- V slice of QKV (B,T,3072) -> VT (B,G,HD,T) bf16 ----------------
__global__ __launch_bounds__(256) void k_v_transpose(const ushort* __restrict__ qkv,
                                                     ushort* __restrict__ out) {
  __shared__ ushort t[32][33];
  int tx = threadIdx.x & 31, ty = threadIdx.x >> 5;
  int t0 = blockIdx.x * 32, d0 = blockIdx.y * 32;
  int b = blockIdx.z >> 2, g = blockIdx.z & 3;
#pragma unroll
  for (int i = 0; i < 4; i++)
    t[ty + i * 8][tx] =
        qkv[((size_t)b * 2048 + t0 + ty + i * 8) * 3072 + 2560 + g * 128 + d0 + tx];
  __syncthreads();
#pragma unroll
  for (int i = 0; i < 4; i++)
    out[(((size_t)b * 4 + g) * 128 + d0 + ty + i * 8) * 2048 + t0 + tx] = t[tx][ty + i * 8];
}

// ---------------- GEMM: C[M,N] = A[M,K] @ BT[N,K]^T, bf16 in, bf16/f32 out ----------------
template <int F32OUT>
__global__ __launch_bounds__(256) void k_gemm(const ushort* __restrict__ A,
                                              const ushort* __restrict__ BT,
                                              void* __restrict__ C, int M, int N, int K) {
  __shared__ ushort As[128 * 32];
  __shared__ ushort Bs[128 * 32];
  const int tid = threadIdx.x;
  const int lane = tid & 63;
  const int wid = tid >> 6;
  int nwg = gridDim.x * gridDim.y;
  int lin = blockIdx.y * gridDim.x + blockIdx.x;
  int swz = (lin & 7) * (nwg >> 3) + (lin >> 3);
  int bx = swz % gridDim.x;
  int by = swz / gridDim.x;
  const int m0 = by * 128, n0 = bx * 128;
  const int wr = (wid >> 1) * 64, wc = (wid & 1) * 64;
  const int l15 = lane & 15, l4 = lane >> 4;
  f32x4 acc[4][4] = {};

  for (int kt = 0; kt < K; kt += 32) {
#pragma unroll
    for (int i = 0; i < 2; i++) {
      int c = i * 256 + tid;
      int row = c >> 2, off = (c & 3) * 8;
      gld16(&A[(size_t)(m0 + row) * K + kt + off], &As[c * 8]);
      gld16(&BT[(size_t)(n0 + row) * K + kt + off], &Bs[c * 8]);
    }
    __syncthreads();
    short8 af[4], bfr[4];
#pragma unroll
    for (int x = 0; x < 4; x++) {
      af[x]  = *(const short8*)&As[(wr + x * 16 + l15) * 32 + l4 * 8];
      bfr[x] = *(const short8*)&Bs[(wc + x * 16 + l15) * 32 + l4 * 8];
    }
#pragma unroll
    for (int mf = 0; mf < 4; mf++)
#pragma unroll
      for (int nf = 0; nf < 4; nf++)
        acc[mf][nf] = __builtin_amdgcn_mfma_f32_16x16x32_bf16(af[mf], bfr[nf], acc[mf][nf], 0, 0, 0);
    __syncthreads();
  }
#pragma unroll
  for (int mf = 0; mf < 4; mf++)
#pragma unroll
    for (int nf = 0; nf < 4; nf++)
#pragma unroll
      for (int r = 0; r < 4; r++) {
        int m = m0 + wr + mf * 16 + l4 * 4 + r;
        int n = n0 + wc + nf * 16 + l15;
        if (F32OUT)
          ((float*)C)[(size_t)m * N + n] = acc[mf][nf][r];
        else
          ((ushort*)C)[(size_t)m * N + n] = f2bf(acc[mf][nf][r]);
      }
}

// K tile stage: LDS[r][c] = Kt[r][c ^ ((r&7)<<3)], linear dest, swizzled source.
__device__ __forceinline__ void stage_k(const ushort* Kt, ushort* Ks, int lane) {
  int rsub = lane >> 4;            // 0..3
  int c0 = (lane & 15) * 8;        // 0..120
#pragma unroll
  for (int n = 0; n < 16; n++) {
    int r = n * 4 + rsub;
    int cs = c0 ^ ((r & 7) << 3);
    gld16(Kt + (size_t)r * 3072 + cs, Ks + n * 512 + lane * 8);
  }
}

// V tile stage: LDS[d][c] = Vt[d][c ^ ((d&7)<<3)]  (Vt row-stride T=2048)
__device__ __forceinline__ void stage_v(const ushort* Vt, ushort* Vs, int lane) {
  int dsub = lane >> 3;            // 0..7
  int c0 = (lane & 7) * 8;         // 0..56
  int cs = c0 ^ (dsub << 3);
#pragma unroll
  for (int n = 0; n < 16; n++) {
    int d = n * 8 + dsub;
    gld16(Vt + (size_t)d * 2048 + cs, Vs + n * 512 + lane * 8);
  }
}

// ---------------- causal GQA flash attention: 1 wave/block, paired q-tiles,
// K/V tiles staged to LDS via global_load_lds DMA (zero VGPR, 1 vmcnt wait/tile),
// XOR-swizzled (both-sides) to kill ds_read bank conflicts. No barriers.
// Prefetch: K(t+1) issued after max-reduce, V(t+1) at tile end.
__global__ __launch_bounds__(64) void k_attn(const ushort* __restrict__ QKV,
                                             const ushort* __restrict__ VT,
                                             ushort* __restrict__ O) {
  const int T = 2048, HD = 128, G = 4, H = 16, RS = 3072;
  const float SCALE2 = 0.08838834764831845f * 1.4426950408889634f;
  int bid = blockIdx.x;
  int p = bid >> 6;          // 0..31
  int bh = bid & 63;
  int h = bh & 15, b = bh >> 4;
  int g = h & 3;
  int lane = threadIdx.x;
  int l15 = lane & 15, l4 = lane >> 4;
  int kswz = (l15 & 7) << 3;

  __shared__ ushort Ks[64 * 128];   // 16KB
  __shared__ ushort Vs[128 * 64];   // 16KB
  __shared__ ushort Ps[32 * 72];    // 4.5KB

  const ushort* Qb = &QKV[(size_t)b * T * RS + h * HD];
  const ushort* Kb = &QKV[(size_t)b * T * RS + 2048 + g * HD];
  const ushort* Vb = &VT[((size_t)b * G + g) * (size_t)HD * T];

  for (int half = 0; half < 2; half++) {
    int j = half ? p : (63 - p);
    int qw = j * 32;

    short8 qf[2][4];
#pragma unroll
    for (int mf = 0; mf < 2; mf++)
#pragma unroll
      for (int kf = 0; kf < 4; kf++)
        qf[mf][kf] = *(const short8*)&Qb[(size_t)(qw + mf * 16 + l15) * RS + kf * 32 + l4 * 8];

    f32x4 o[2][8] = {};
    float mrow[8], lrow[8];
#pragma unroll
    for (int i = 0; i < 8; i++) { mrow[i] = -3e38f; lrow[i] = 0.f; }

    int ntiles = (qw >> 6) + 1;
    stage_k(Kb, Ks, lane);
    stage_v(Vb, Vs, lane);

    for (int it = 0; it < ntiles; ++it) {
      int t0 = it * 64;
      asm volatile("s_waitcnt vmcnt(0)" ::: "memory");
      __builtin_amdgcn_sched_barrier(0);

      f32x4 s[2][4] = {};
#pragma unroll
      for (int kf = 0; kf < 4; kf++) {
#pragma unroll
        for (int nf = 0; nf < 4; nf++) {
          short8 bk = *(const short8*)&Ks[(nf * 16 + l15) * 128 + ((kf * 32 + l4 * 8) ^ kswz)];
          s[0][nf] = __builtin_amdgcn_mfma_f32_16x16x32_bf16(qf[0][kf], bk, s[0][nf], 0, 0, 0);
          s[1][nf] = __builtin_amdgcn_mfma_f32_16x16x32_bf16(qf[1][kf], bk, s[1][nf], 0, 0, 0);
        }
      }
      bool needmask = (t0 + 63 > qw);
#pragma unroll
      for (int mf = 0; mf < 2; mf++)
#pragma unroll
        for (int nf = 0; nf < 4; nf++)
#pragma unroll
          for (int r = 0; r < 4; r++) {
            float v = s[mf][nf][r] * SCALE2;
            if (needmask) {
              int qq = qw + mf * 16 + l4 * 4 + r;
              int kk = t0 + nf * 16 + l15;
              if (kk > qq) v = -1e30f;
            }
            s[mf][nf][r] = v;
          }
      float scs[8];
#pragma unroll
      for (int mf = 0; mf < 2; mf++)
#pragma unroll
        for (int r = 0; r < 4; r++) {
          int i = mf * 4 + r;
          float x = fmaxf(fmaxf(s[mf][0][r], s[mf][1][r]), fmaxf(s[mf][2][r], s[mf][3][r]));
          x = fmaxf(x, __shfl_xor(x, 1));
          x = fmaxf(x, __shfl_xor(x, 2));
          x = fmaxf(x, __shfl_xor(x, 4));
          x = fmaxf(x, __shfl_xor(x, 8));
          float mn = fmaxf(mrow[i], x);
          scs[i] = fexp2(mrow[i] - mn);
          mrow[i] = mn;
        }
      // K LDS consumed (QK MFMAs issued); prefetch next K under softmax tail + PV
      if (it + 1 < ntiles) {
        asm volatile("s_waitcnt lgkmcnt(0)" ::: "memory");
        __builtin_amdgcn_sched_barrier(0);
        stage_k(Kb + (size_t)(t0 + 64) * RS, Ks, lane);
        __builtin_amdgcn_sched_barrier(0);
      }
      float rs[8];
#pragma unroll
      for (int i = 0; i < 8; i++) rs[i] = 0.f;
#pragma unroll
      for (int mf = 0; mf < 2; mf++)
#pragma unroll
        for (int nf = 0; nf < 4; nf++)
#pragma unroll
          for (int r = 0; r < 4; r++) {
            float pq = fexp2(s[mf][nf][r] - mrow[mf * 4 + r]);
            s[mf][nf][r] = pq;
            rs[mf * 4 + r] += pq;
          }
#pragma unroll
      for (int i = 0; i < 8; i++) lrow[i] = lrow[i] * scs[i] + rs[i];
#pragma unroll
      for (int mf = 0; mf < 2; mf++)
#pragma unroll
        for (int nfo = 0; nfo < 8; nfo++)
#pragma unroll
          for (int r = 0; r < 4; r++)
            o[mf][nfo][r] *= scs[mf * 4 + r];
#pragma unroll
      for (int mf = 0; mf < 2; mf++)
#pragma unroll
        for (int nf = 0; nf < 4; nf++)
#pragma unroll
          for (int r = 0; r < 4; r++)
            Ps[(mf * 16 + l4 * 4 + r) * 72 + nf * 16 + l15] = f2bf(s[mf][nf][r]);
#pragma unroll
      for (int kf = 0; kf < 2; kf++) {
        short8 pa0 = *(const short8*)&Ps[(l15) * 72 + kf * 32 + l4 * 8];
        short8 pa1 = *(const short8*)&Ps[(16 + l15) * 72 + kf * 32 + l4 * 8];
#pragma unroll
        for (int nfo = 0; nfo < 8; nfo++) {
          short8 bv = *(const short8*)&Vs[(nfo * 16 + l15) * 64 + ((kf * 32 + l4 * 8) ^ kswz)];
          o[0][nfo] = __builtin_amdgcn_mfma_f32_16x16x32_bf16(pa0, bv, o[0][nfo], 0, 0, 0);
          o[1][nfo] = __builtin_amdgcn_mfma_f32_16x16x32_bf16(pa1, bv, o[1][nfo], 0, 0, 0);
        }
      }
      // V LDS consumed (PV MFMAs issued); prefetch next V
      if (it + 1 < ntiles) {
        asm volatile("s_waitcnt lgkmcnt(0)" ::: "memory");
        __builtin_amdgcn_sched_barrier(0);
        stage_v(Vb + t0 + 64, Vs, lane);
        __builtin_amdgcn_sched_barrier(0);
      }
    }

    // finish deferred 16-lane reduction of l
#pragma unroll
    for (int i = 0; i < 8; i++) {
      float x = lrow[i];
      x += __shfl_xor(x, 1);
      x += __shfl_xor(x, 2);
      x += __shfl_xor(x, 4);
      x += __shfl_xor(x, 8);
      lrow[i] = x;
    }
    float inv[8];
#pragma unroll
    for (int i = 0; i < 8; i++) inv[i] = 1.0f / lrow[i];
#pragma unroll
    for (int mf = 0; mf < 2; mf++)
#pragma unroll
      for (int nfo = 0; nfo < 8; nfo++)
#pragma unroll
        for (int r = 0; r < 4; r++) {
          int t = qw + mf * 16 + l4 * 4 + r;
          int d = nfo * 16 + l15;
          O[(((size_t)b * T + t) * H + h) * HD + d] = f2bf(o[mf][nfo][r] * inv[mf * 4 + r]);
        }
  }
}

extern "C" void kernel_launch(void* const* d_in, const int* in_sizes, int n_in,
                              void* d_out, int out_size, void* d_ws, size_t ws_size,
                              hipStream_t stream) {
  const float* x   = (const float*)d_in[0];
  const float* w_q = (const float*)d_in[1];
  const float* w_k = (const float*)d_in[2];
  const float* w_v = (const float*)d_in[3];
  const float* w_o = (const float*)d_in[4];

  char* ws = (char*)d_ws;
  ushort* xbf  = (ushort*)(ws);                // 32MB (reused as attn out)
  ushort* wkvT = (ushort*)(ws + 33554432ul);   // 12MB: [wq|wk|wv]^T = [3072,2048]
  ushort* woT  = (ushort*)(ws + 46137344ul);   // 8MB
  ushort* qkvb = (ushort*)(ws + 54525952ul);   // 48MB: (B,T,3072)
  ushort* VTb  = (ushort*)(ws + 104857600ul);  // 8MB  (total 113,246,208 B)
  ushort* attn = xbf;

  k_f32_to_bf16<<<8192, 256, 0, stream>>>(x, xbf, 16777216L);
  k_w_transpose<<<dim3(64, 64), 256, 0, stream>>>(w_q, wkvT, 2048, 2048);
  k_w_transpose<<<dim3(16, 64), 256, 0, stream>>>(w_k, wkvT + 2048ul * 2048, 2048, 512);
  k_w_transpose<<<dim3(16, 64), 256, 0, stream>>>(w_v, wkvT + 2560ul * 2048, 2048, 512);
  k_w_transpose<<<dim3(64, 64), 256, 0, stream>>>(w_o, woT, 2048, 2048);

  // merged QKV projection: one dispatch, N=3072
  k_gemm<0><<<dim3(24, 64), 256, 0, stream>>>(xbf, wkvT, qkvb, 8192, 3072, 2048);

  k_v_transpose<<<dim3(64, 4, 16), 256, 0, stream>>>(qkvb, VTb);

  k_attn<<<2048, 64, 0, stream>>>(qkvb, VTb, attn);

  k_gemm<1><<<dim3(16, 64), 256, 0, stream>>>(attn, woT, (float*)d_out, 8192, 2048, 2048);
}

// Round 10
// 406.935 us; speedup vs baseline: 1.3820x; 1.3820x over previous
//
#include <hip/hip_runtime.h>
#include <stdint.h>

typedef __attribute__((ext_vector_type(8))) short short8;
typedef __attribute__((ext_vector_type(8))) unsigned short ushort8;
typedef __attribute__((ext_vector_type(4))) float f32x4;

__device__ __forceinline__ ushort f2bf(float f) {
  union { float f; uint32_t u; } v; v.f = f;
  uint32_t r = v.u + 0x7FFFu + ((v.u >> 16) & 1u);
  return (ushort)(r >> 16);
}

__device__ __forceinline__ float fexp2(float x) {  // 2^x, single v_exp_f32
  float r;
  asm("v_exp_f32 %0, %1" : "=v"(r) : "v"(x));
  return r;
}

__device__ __forceinline__ void gld16(const ushort* g, ushort* l) {
  __builtin_amdgcn_global_load_lds((const __attribute__((address_space(1))) void*)g,
                                   (__attribute__((address_space(3))) void*)l, 16, 0, 0);
}

// ---------------- fp32 -> bf16 elementwise ----------------
__global__ __launch_bounds__(256) void k_f32_to_bf16(const float* __restrict__ in,
                                                     ushort* __restrict__ out, long n) {
  long i = ((long)blockIdx.x * 256 + threadIdx.x) * 8;
  if (i >= n) return;
  float4 a = *(const float4*)(in + i);
  float4 b = *(const float4*)(in + i + 4);
  ushort8 o;
  o[0] = f2bf(a.x); o[1] = f2bf(a.y); o[2] = f2bf(a.z); o[3] = f2bf(a.w);
  o[4] = f2bf(b.x); o[5] = f2bf(b.y); o[6] = f2bf(b.z); o[7] = f2bf(b.w);
  *(ushort8*)(out + i) = o;
}

// ---------------- fp32 (R x C) -> bf16 transposed (C x R), out row-stride R ----------------
__global__ __launch_bounds__(256) void k_w_transpose(const float* __restrict__ in,
                                                     ushort* __restrict__ out, int R, int C) {
  __shared__ float t[32][33];
  int tx = threadIdx.x & 31, ty = threadIdx.x >> 5;
  int r0 = blockIdx.y * 32, c0 = blockIdx.x * 32;
#pragma unroll
  for (int i = 0; i < 4; i++)
    t[ty + i * 8][tx] = in[(size_t)(r0 + ty + i * 8) * C + c0 + tx];
  __syncthreads();
#pragma unroll
  for (int i = 0; i < 4; i++)
    out[(size_t)(c0 + ty + i * 8) * R + r0 + tx] = f2bf(t[tx][ty + i * 8]);
}

// ---------------- V slice of QKV (B,T,3072) -> VT (B,G,HD,T) bf16 ----------------
__global__ __launch_bounds__(256) void k_v_transpose(const ushort* __restrict__ qkv,
                                                     ushort* __restrict__ out) {
  __shared__ ushort t[32][33];
  int tx = threadIdx.x & 31, ty = threadIdx.x >> 5;
  int t0 = blockIdx.x * 32, d0 = blockIdx.y * 32;
  int b = blockIdx.z >> 2, g = blockIdx.z & 3;
#pragma unroll
  for (int i = 0; i < 4; i++)
    t[ty + i * 8][tx] =
        qkv[((size_t)b * 2048 + t0 + ty + i * 8) * 3072 + 2560 + g * 128 + d0 + tx];
  __syncthreads();
#pragma unroll
  for (int i = 0; i < 4; i++)
    out[(((size_t)b * 4 + g) * 128 + d0 + ty + i * 8) * 2048 + t0 + tx] = t[tx][ty + i * 8];
}

// ---------------- GEMM: C[M,N] = A[M,K] @ BT[N,K]^T, bf16 in, bf16/f32 out ----------------
template <int F32OUT>
__global__ __launch_bounds__(256) void k_gemm(const ushort* __restrict__ A,
                                              const ushort* __restrict__ BT,
                                              void* __restrict__ C, int M, int N, int K) {
  __shared__ ushort As[128 * 32];
  __shared__ ushort Bs[128 * 32];
  const int tid = threadIdx.x;
  const int lane = tid & 63;
  const int wid = tid >> 6;
  int nwg = gridDim.x * gridDim.y;
  int lin = blockIdx.y * gridDim.x + blockIdx.x;
  int swz = (lin & 7) * (nwg >> 3) + (lin >> 3);
  int bx = swz % gridDim.x;
  int by = swz / gridDim.x;
  const int m0 = by * 128, n0 = bx * 128;
  const int wr = (wid >> 1) * 64, wc = (wid & 1) * 64;
  const int l15 = lane & 15, l4 = lane >> 4;
  f32x4 acc[4][4] = {};

  for (int kt = 0; kt < K; kt += 32) {
#pragma unroll
    for (int i = 0; i < 2; i++) {
      int c = i * 256 + tid;
      int row = c >> 2, off = (c & 3) * 8;
      gld16(&A[(size_t)(m0 + row) * K + kt + off], &As[c * 8]);
      gld16(&BT[(size_t)(n0 + row) * K + kt + off], &Bs[c * 8]);
    }
    __syncthreads();
    short8 af[4], bfr[4];
#pragma unroll
    for (int x = 0; x < 4; x++) {
      af[x]  = *(const short8*)&As[(wr + x * 16 + l15) * 32 + l4 * 8];
      bfr[x] = *(const short8*)&Bs[(wc + x * 16 + l15) * 32 + l4 * 8];
    }
#pragma unroll
    for (int mf = 0; mf < 4; mf++)
#pragma unroll
      for (int nf = 0; nf < 4; nf++)
        acc[mf][nf] = __builtin_amdgcn_mfma_f32_16x16x32_bf16(af[mf], bfr[nf], acc[mf][nf], 0, 0, 0);
    __syncthreads();
  }
#pragma unroll
  for (int mf = 0; mf < 4; mf++)
#pragma unroll
    for (int nf = 0; nf < 4; nf++)
#pragma unroll
      for (int r = 0; r < 4; r++) {
        int m = m0 + wr + mf * 16 + l4 * 4 + r;
        int n = n0 + wc + nf * 16 + l15;
        if (F32OUT)
          ((float*)C)[(size_t)m * N + n] = acc[mf][nf][r];
        else
          ((ushort*)C)[(size_t)m * N + n] = f2bf(acc[mf][nf][r]);
      }
}

// K tile stage (shared across 8 waves, 2 DMA lines per thread):
// LDS linear [64][128], source col pre-swizzled c ^ ((r&7)<<3). Kt row stride 3072.
__device__ __forceinline__ void stage_k8(const ushort* Kt, ushort* Ks, int tid) {
  int l = tid & 63, w = tid >> 6;
#pragma unroll
  for (int n = 0; n < 2; n++) {
    int cidx = w * 2 + n;
    int r = cidx * 4 + (l >> 4);
    int cs = ((l & 15) * 8) ^ ((r & 7) << 3);
    gld16(Kt + (size_t)r * 3072 + cs, Ks + cidx * 512 + l * 8);
  }
}

// V tile stage: LDS linear [128][64] (d-major), source col (within 64 keys)
// pre-swizzled kc ^ ((d&7)<<3). Vt row stride T=2048.
__device__ __forceinline__ void stage_v8(const ushort* Vt, ushort* Vs, int tid) {
  int l = tid & 63, w = tid >> 6;
#pragma unroll
  for (int n = 0; n < 2; n++) {
    int cidx = w * 2 + n;
    int d = cidx * 8 + (l >> 3);
    int cs = ((l & 7) * 8) ^ ((d & 7) << 3);
    gld16(Vt + (size_t)d * 2048 + cs, Vs + cidx * 512 + l * 8);
  }
}

// ---------------- causal GQA flash attention: 8-wave blocks, shared K/V LDS ------
// Block = 512 threads = 8 waves = 256 q-rows (wave w owns rows chunk*256+w*32..+32).
// K/V 64-key tile staged ONCE per block (8x amortized vs 1-wave design), double-
// buffered; catalog 2-phase: {stage(it+1)->alt; compute(it); __syncthreads()} --
// barrier's vmcnt(0) drains a stage that had the whole compute phase to land.
// Causal balance: block handles q-chunks (7-pr) then pr -> 36 tiles for ALL blocks.
// XOR swizzles both-sides (rule #21, proven R9). softmax in exp2 domain.
__global__ __launch_bounds__(512) void k_attn(const ushort* __restrict__ QKV,
                                              const ushort* __restrict__ VT,
                                              ushort* __restrict__ O) {
  const int T = 2048, HD = 128, G = 4, H = 16, RS = 3072;
  const float SCALE2 = 0.08838834764831845f * 1.4426950408889634f;
  int bid = blockIdx.x;
  int pr = bid >> 6;         // 0..3 chunk-pair index
  int bh = bid & 63;         // low bits -> XCD spread keeps ~one g per XCD (L2-sized)
  int h = bh & 15, b = bh >> 4;
  int g = h & 3;
  int tid = threadIdx.x, wid = tid >> 6, lane = tid & 63;
  int l15 = lane & 15, l4 = lane >> 4;
  int kswz = (l15 & 7) << 3;

  __shared__ __align__(16) char smem[102400];
  ushort* Ks0 = (ushort*)smem;                 // 16KB [64][128]
  ushort* Ks1 = (ushort*)(smem + 16384);
  ushort* Vs0 = (ushort*)(smem + 32768);       // 16KB [128][64]
  ushort* Vs1 = (ushort*)(smem + 49152);
  ushort* Pw  = (ushort*)(smem + 65536) + wid * (32 * 72);  // per-wave P stage

  const ushort* Qb = &QKV[(size_t)b * T * RS + h * HD];
  const ushort* Kb = &QKV[(size_t)b * T * RS + 2048 + g * HD];
  const ushort* Vb = &VT[((size_t)b * G + g) * (size_t)HD * T];

#pragma unroll 1
  for (int half = 0; half < 2; half++) {
    int ch = half ? pr : (7 - pr);
    int qw = ch * 256 + wid * 32;
    int nt = 4 * (ch + 1);

    short8 qf[2][4];
#pragma unroll
    for (int mf = 0; mf < 2; mf++)
#pragma unroll
      for (int kf = 0; kf < 4; kf++)
        qf[mf][kf] = *(const short8*)&Qb[(size_t)(qw + mf * 16 + l15) * RS + kf * 32 + l4 * 8];

    f32x4 o[2][8] = {};
    float mrow[8], lrow[8];
#pragma unroll
    for (int i = 0; i < 8; i++) { mrow[i] = -3e38f; lrow[i] = 0.f; }

    // prologue: stage tile 0 into buf0
    stage_k8(Kb, Ks0, tid);
    stage_v8(Vb, Vs0, tid);
    __syncthreads();

#pragma unroll 1
    for (int it = 0; it < nt; ++it) {
      int t0 = it * 64;
      int cur = it & 1;
      ushort* Kc = cur ? Ks1 : Ks0;
      ushort* Vc = cur ? Vs1 : Vs0;
      if (it + 1 < nt) {  // prefetch next tile into alt buffer (in flight over compute)
        stage_k8(Kb + (size_t)(t0 + 64) * RS, cur ? Ks0 : Ks1, tid);
        stage_v8(Vb + t0 + 64, cur ? Vs0 : Vs1, tid);
      }
      if (t0 <= qw + 31) {  // not fully masked for this wave
        f32x4 s[2][4] = {};
#pragma unroll
        for (int kf = 0; kf < 4; kf++) {
#pragma unroll
          for (int nf = 0; nf < 4; nf++) {
            short8 bk = *(const short8*)&Kc[(nf * 16 + l15) * 128 + ((kf * 32 + l4 * 8) ^ kswz)];
            s[0][nf] = __builtin_amdgcn_mfma_f32_16x16x32_bf16(qf[0][kf], bk, s[0][nf], 0, 0, 0);
            s[1][nf] = __builtin_amdgcn_mfma_f32_16x16x32_bf16(qf[1][kf], bk, s[1][nf], 0, 0, 0);
          }
        }
        bool needmask = (t0 + 63 > qw);
#pragma unroll
        for (int mf = 0; mf < 2; mf++)
#pragma unroll
          for (int nf = 0; nf < 4; nf++)
#pragma unroll
            for (int r = 0; r < 4; r++) {
              float v = s[mf][nf][r] * SCALE2;
              if (needmask) {
                int qq = qw + mf * 16 + l4 * 4 + r;
                int kk = t0 + nf * 16 + l15;
                if (kk > qq) v = -1e30f;
              }
              s[mf][nf][r] = v;
            }
        float scs[8];
#pragma unroll
        for (int mf = 0; mf < 2; mf++)
#pragma unroll
          for (int r = 0; r < 4; r++) {
            int i = mf * 4 + r;
            float x = fmaxf(fmaxf(s[mf][0][r], s[mf][1][r]), fmaxf(s[mf][2][r], s[mf][3][r]));
            x = fmaxf(x, __shfl_xor(x, 1));
            x = fmaxf(x, __shfl_xor(x, 2));
            x = fmaxf(x, __shfl_xor(x, 4));
            x = fmaxf(x, __shfl_xor(x, 8));
            float mn = fmaxf(mrow[i], x);
            scs[i] = fexp2(mrow[i] - mn);
            mrow[i] = mn;
          }
        float rs[8];
#pragma unroll
        for (int i = 0; i < 8; i++) rs[i] = 0.f;
#pragma unroll
        for (int mf = 0; mf < 2; mf++)
#pragma unroll
          for (int nf = 0; nf < 4; nf++)
#pragma unroll
            for (int r = 0; r < 4; r++) {
              float pq = fexp2(s[mf][nf][r] - mrow[mf * 4 + r]);
              s[mf][nf][r] = pq;
              rs[mf * 4 + r] += pq;
            }
#pragma unroll
        for (int i = 0; i < 8; i++) lrow[i] = lrow[i] * scs[i] + rs[i];
#pragma unroll
        for (int mf = 0; mf < 2; mf++)
#pragma unroll
          for (int nfo = 0; nfo < 8; nfo++)
#pragma unroll
            for (int r = 0; r < 4; r++)
              o[mf][nfo][r] *= scs[mf * 4 + r];
#pragma unroll
        for (int mf = 0; mf < 2; mf++)
#pragma unroll
          for (int nf = 0; nf < 4; nf++)
#pragma unroll
            for (int r = 0; r < 4; r++)
              Pw[(mf * 16 + l4 * 4 + r) * 72 + nf * 16 + l15] = f2bf(s[mf][nf][r]);
#pragma unroll
        for (int kf = 0; kf < 2; kf++) {
          short8 pa0 = *(const short8*)&Pw[(l15) * 72 + kf * 32 + l4 * 8];
          short8 pa1 = *(const short8*)&Pw[(16 + l15) * 72 + kf * 32 + l4 * 8];
#pragma unroll
          for (int nfo = 0; nfo < 8; nfo++) {
            short8 bv = *(const short8*)&Vc[(nfo * 16 + l15) * 64 + ((kf * 32 + l4 * 8) ^ kswz)];
            o[0][nfo] = __builtin_amdgcn_mfma_f32_16x16x32_bf16(pa0, bv, o[0][nfo], 0, 0, 0);
            o[1][nfo] = __builtin_amdgcn_mfma_f32_16x16x32_bf16(pa1, bv, o[1][nfo], 0, 0, 0);
          }
        }
      }
      __syncthreads();  // drains stage(it+1) DMA (vmcnt0) + closes all LDS reads
    }

    // epilogue: finish deferred 16-lane reduction of l, normalize, store
#pragma unroll
    for (int i = 0; i < 8; i++) {
      float x = lrow[i];
      x += __shfl_xor(x, 1);
      x += __shfl_xor(x, 2);
      x += __shfl_xor(x, 4);
      x += __shfl_xor(x, 8);
      lrow[i] = x;
    }
    float inv[8];
#pragma unroll
    for (int i = 0; i < 8; i++) inv[i] = 1.0f / lrow[i];
#pragma unroll
    for (int mf = 0; mf < 2; mf++)
#pragma unroll
      for (int nfo = 0; nfo < 8; nfo++)
#pragma unroll
        for (int r = 0; r < 4; r++) {
          int t = qw + mf * 16 + l4 * 4 + r;
          int d = nfo * 16 + l15;
          O[(((size_t)b * T + t) * H + h) * HD + d] = f2bf(o[mf][nfo][r] * inv[mf * 4 + r]);
        }
    __syncthreads();  // all waves done before next chunk's prologue staging
  }
}

extern "C" void kernel_launch(void* const* d_in, const int* in_sizes, int n_in,
                              void* d_out, int out_size, void* d_ws, size_t ws_size,
                              hipStream_t stream) {
  const float* x   = (const float*)d_in[0];
  const float* w_q = (const float*)d_in[1];
  const float* w_k = (const float*)d_in[2];
  const float* w_v = (const float*)d_in[3];
  const float* w_o = (const float*)d_in[4];

  char* ws = (char*)d_ws;
  ushort* xbf  = (ushort*)(ws);                // 32MB (reused as attn out)
  ushort* wkvT = (ushort*)(ws + 33554432ul);   // 12MB: [wq|wk|wv]^T = [3072,2048]
  ushort* woT  = (ushort*)(ws + 46137344ul);   // 8MB
  ushort* qkvb = (ushort*)(ws + 54525952ul);   // 48MB: (B,T,3072)
  ushort* VTb  = (ushort*)(ws + 104857600ul);  // 8MB  (total 113,246,208 B)
  ushort* attn = xbf;

  k_f32_to_bf16<<<8192, 256, 0, stream>>>(x, xbf, 16777216L);
  k_w_transpose<<<dim3(64, 64), 256, 0, stream>>>(w_q, wkvT, 2048, 2048);
  k_w_transpose<<<dim3(16, 64), 256, 0, stream>>>(w_k, wkvT + 2048ul * 2048, 2048, 512);
  k_w_transpose<<<dim3(16, 64), 256, 0, stream>>>(w_v, wkvT + 2560ul * 2048, 2048, 512);
  k_w_transpose<<<dim3(64, 64), 256, 0, stream>>>(w_o, woT, 2048, 2048);

  // merged QKV projection: one dispatch, N=3072
  k_gemm<0><<<dim3(24, 64), 256, 0, stream>>>(xbf, wkvT, qkvb, 8192, 3072, 2048);

  k_v_transpose<<<dim3(64, 4, 16), 256, 0, stream>>>(qkvb, VTb);

  k_attn<<<256, 512, 0, stream>>>(qkvb, VTb, attn);

  k_gemm<1><<<dim3(16, 64), 256, 0, stream>>>(attn, woT, (float*)d_out, 8192, 2048, 2048);
}

// Round 11
// 376.482 us; speedup vs baseline: 1.4937x; 1.0809x over previous
//
#include <hip/hip_runtime.h>
#include <stdint.h>

typedef __attribute__((ext_vector_type(8))) short short8;
typedef __attribute__((ext_vector_type(8))) unsigned short ushort8;
typedef __attribute__((ext_vector_type(4))) float f32x4;

__device__ __forceinline__ ushort f2bf(float f) {
  union { float f; uint32_t u; } v; v.f = f;
  uint32_t r = v.u + 0x7FFFu + ((v.u >> 16) & 1u);
  return (ushort)(r >> 16);
}

__device__ __forceinline__ float fexp2(float x) {  // 2^x, single v_exp_f32
  float r;
  asm("v_exp_f32 %0, %1" : "=v"(r) : "v"(x));
  return r;
}

__device__ __forceinline__ void gld16(const ushort* g, ushort* l) {
  __builtin_amdgcn_global_load_lds((const __attribute__((address_space(1))) void*)g,
                                   (__attribute__((address_space(3))) void*)l, 16, 0, 0);
}

// ---------------- fp32 -> bf16 elementwise ----------------
__global__ __launch_bounds__(256) void k_f32_to_bf16(const float* __restrict__ in,
                                                     ushort* __restrict__ out, long n) {
  long i = ((long)blockIdx.x * 256 + threadIdx.x) * 8;
  if (i >= n) return;
  float4 a = *(const float4*)(in + i);
  float4 b = *(const float4*)(in + i + 4);
  ushort8 o;
  o[0] = f2bf(a.x); o[1] = f2bf(a.y); o[2] = f2bf(a.z); o[3] = f2bf(a.w);
  o[4] = f2bf(b.x); o[5] = f2bf(b.y); o[6] = f2bf(b.z); o[7] = f2bf(b.w);
  *(ushort8*)(out + i) = o;
}

// ---------------- fp32 (R x C) -> bf16 transposed (C x R), out row-stride R ----------------
__global__ __launch_bounds__(256) void k_w_transpose(const float* __restrict__ in,
                                                     ushort* __restrict__ out, int R, int C) {
  __shared__ float t[32][33];
  int tx = threadIdx.x & 31, ty = threadIdx.x >> 5;
  int r0 = blockIdx.y * 32, c0 = blockIdx.x * 32;
#pragma unroll
  for (int i = 0; i < 4; i++)
    t[ty + i * 8][tx] = in[(size_t)(r0 + ty + i * 8) * C + c0 + tx];
  __syncthreads();
#pragma unroll
  for (int i = 0; i < 4; i++)
    out[(size_t)(c0 + ty + i * 8) * R + r0 + tx] = f2bf(t[tx][ty + i * 8]);
}

// ---------------- V slice of QKV (B,T,3072) -> VT (B,G,HD,T) bf16 ----------------
__global__ __launch_bounds__(256) void k_v_transpose(const ushort* __restrict__ qkv,
                                                     ushort* __restrict__ out) {
  __shared__ ushort t[32][33];
  int tx = threadIdx.x & 31, ty = threadIdx.x >> 5;
  int t0 = blockIdx.x * 32, d0 = blockIdx.y * 32;
  int b = blockIdx.z >> 2, g = blockIdx.z & 3;
#pragma unroll
  for (int i = 0; i < 4; i++)
    t[ty + i * 8][tx] =
        qkv[((size_t)b * 2048 + t0 + ty + i * 8) * 3072 + 2560 + g * 128 + d0 + tx];
  __syncthreads();
#pragma unroll
  for (int i = 0; i < 4; i++)
    out[(((size_t)b * 4 + g) * 128 + d0 + ty + i * 8) * 2048 + t0 + tx] = t[tx][ty + i * 8];
}

// Stage one 256x64 bf16 tile (32KB) into LDS: 512 threads x 4 gld16.
// LDS linear [256][64]; global source col pre-XOR'd so LDS[r][c]=G[r][c^((r&7)<<3)].
__device__ __forceinline__ void stage256(const ushort* G, int ldg, ushort* Ls, int tid) {
  int l = tid & 63, w = tid >> 6;
  int rsub = l >> 3;                         // row within 8-row chunk
  int cs = ((l & 7) ^ rsub) << 3;            // pre-swizzled ushort col
#pragma unroll
  for (int n = 0; n < 4; n++) {
    int c = n * 8 + w;                       // chunk 0..31
    gld16(G + (size_t)(c * 8 + rsub) * ldg + cs, Ls + c * 512 + l * 8);
  }
}

// ---------------- 256x256 GEMM, BK=64, counted-vmcnt double-buffer pipeline ------
// C[M,N] = A[M,K] @ BT[N,K]^T. 8 waves (2Mx4N), per-wave 128x64 out, acc[8][4].
// Per K-tile: 4 quadrant phases (ds_read frags + 16 MFMA) -> s_barrier ->
// stage(kt+2) into just-freed buffer -> s_waitcnt vmcnt(8) (kt+1 landed, kt+2 in
// flight; never drains to 0 in steady state, T3+T4) -> s_barrier.
template <int F32OUT>
__global__ __launch_bounds__(512) void k_gemm256(const ushort* __restrict__ A,
                                                 const ushort* __restrict__ BT,
                                                 void* __restrict__ C, int M, int N, int K) {
  __shared__ ushort As0[256 * 64], As1[256 * 64];
  __shared__ ushort Bs0[256 * 64], Bs1[256 * 64];
  const int tid = threadIdx.x;
  const int lane = tid & 63, wid = tid >> 6;
  const int wm = wid >> 2, wn = wid & 3;
  const int l15 = lane & 15, l4 = lane >> 4;
  const int rsw = (l15 & 7) << 3;
  int nwg = gridDim.x * gridDim.y;
  int lin = blockIdx.y * gridDim.x + blockIdx.x;
  int swz = (lin & 7) * (nwg >> 3) + (lin >> 3);
  int bx = swz % gridDim.x, by = swz / gridDim.x;
  const int m0 = by * 256, n0 = bx * 256;

  const ushort* Atile = A + (size_t)m0 * K;
  const ushort* Btile = BT + (size_t)n0 * K;
  const int NK = K >> 6;

  f32x4 acc[8][4] = {};

  // prologue: stage kt0 -> buf0, kt1 -> buf1; wait kt0 (oldest 8), keep kt1 in flight
  stage256(Atile, K, As0, tid);
  stage256(Btile, K, Bs0, tid);
  stage256(Atile + 64, K, As1, tid);
  stage256(Btile + 64, K, Bs1, tid);
  asm volatile("s_waitcnt vmcnt(8)" ::: "memory");
  asm volatile("s_barrier" ::: "memory");

  for (int kt = 0; kt < NK; ++kt) {
    const ushort* Ab = (kt & 1) ? As1 : As0;
    const ushort* Bb = (kt & 1) ? Bs1 : Bs0;
    // B fragments for the whole K-tile (shared across all 4 quadrants)
    short8 bfrag[4][2];
#pragma unroll
    for (int nf = 0; nf < 4; nf++)
#pragma unroll
      for (int ks = 0; ks < 2; ks++)
        bfrag[nf][ks] = *(const short8*)&Bb[(wn * 64 + nf * 16 + l15) * 64 +
                                            ((ks * 32 + l4 * 8) ^ rsw)];
    // 4 quadrant phases
#pragma unroll
    for (int q = 0; q < 4; q++) {
      short8 afr[2][2];
#pragma unroll
      for (int dm = 0; dm < 2; dm++)
#pragma unroll
        for (int ks = 0; ks < 2; ks++)
          afr[dm][ks] = *(const short8*)&Ab[(wm * 128 + (q * 2 + dm) * 16 + l15) * 64 +
                                            ((ks * 32 + l4 * 8) ^ rsw)];
      __builtin_amdgcn_s_setprio(1);
#pragma unroll
      for (int dm = 0; dm < 2; dm++)
#pragma unroll
        for (int nf = 0; nf < 4; nf++)
#pragma unroll
          for (int ks = 0; ks < 2; ks++)
            acc[q * 2 + dm][nf] = __builtin_amdgcn_mfma_f32_16x16x32_bf16(
                afr[dm][ks], bfrag[nf][ks], acc[q * 2 + dm][nf], 0, 0, 0);
      __builtin_amdgcn_s_setprio(0);
    }
    // all reads of buf[kt&1] consumed (MFMA deps forced lgkm waits)
    asm volatile("s_barrier" ::: "memory");
    if (kt + 2 < NK) {
      // refill the just-freed buffer with kt+2; then wait only for kt+1's 8 loads
      stage256(Atile + (kt + 2) * 64, K, (kt & 1) ? As1 : As0, tid);
      stage256(Btile + (kt + 2) * 64, K, (kt & 1) ? Bs1 : Bs0, tid);
      asm volatile("s_waitcnt vmcnt(8)" ::: "memory");
    } else {
      asm volatile("s_waitcnt vmcnt(0)" ::: "memory");
    }
    asm volatile("s_barrier" ::: "memory");
  }

  // epilogue
#pragma unroll
  for (int mf = 0; mf < 8; mf++)
#pragma unroll
    for (int nf = 0; nf < 4; nf++)
#pragma unroll
      for (int r = 0; r < 4; r++) {
        int m = m0 + wm * 128 + mf * 16 + l4 * 4 + r;
        int n = n0 + wn * 64 + nf * 16 + l15;
        if (F32OUT)
          ((float*)C)[(size_t)m * N + n] = acc[mf][nf][r];
        else
          ((ushort*)C)[(size_t)m * N + n] = f2bf(acc[mf][nf][r]);
      }
}

// K tile stage (shared across 8 waves, 2 DMA lines per thread):
// LDS linear [64][128], source col pre-swizzled c ^ ((r&7)<<3). Kt row stride 3072.
__device__ __forceinline__ void stage_k8(const ushort* Kt, ushort* Ks, int tid) {
  int l = tid & 63, w = tid >> 6;
#pragma unroll
  for (int n = 0; n < 2; n++) {
    int cidx = w * 2 + n;
    int r = cidx * 4 + (l >> 4);
    int cs = ((l & 15) * 8) ^ ((r & 7) << 3);
    gld16(Kt + (size_t)r * 3072 + cs, Ks + cidx * 512 + l * 8);
  }
}

// V tile stage: LDS linear [128][64] (d-major), source col (within 64 keys)
// pre-swizzled kc ^ ((d&7)<<3). Vt row stride T=2048.
__device__ __forceinline__ void stage_v8(const ushort* Vt, ushort* Vs, int tid) {
  int l = tid & 63, w = tid >> 6;
#pragma unroll
  for (int n = 0; n < 2; n++) {
    int cidx = w * 2 + n;
    int d = cidx * 8 + (l >> 3);
    int cs = ((l & 7) * 8) ^ ((d & 7) << 3);
    gld16(Vt + (size_t)d * 2048 + cs, Vs + cidx * 512 + l * 8);
  }
}

// ---------------- causal GQA flash attention: 8-wave blocks, shared K/V LDS ------
// (unchanged from round 10: 150.8us verified)
__global__ __launch_bounds__(512) void k_attn(const ushort* __restrict__ QKV,
                                              const ushort* __restrict__ VT,
                                              ushort* __restrict__ O) {
  const int T = 2048, HD = 128, G = 4, H = 16, RS = 3072;
  const float SCALE2 = 0.08838834764831845f * 1.4426950408889634f;
  int bid = blockIdx.x;
  int pr = bid >> 6;
  int bh = bid & 63;
  int h = bh & 15, b = bh >> 4;
  int g = h & 3;
  int tid = threadIdx.x, wid = tid >> 6, lane = tid & 63;
  int l15 = lane & 15, l4 = lane >> 4;
  int kswz = (l15 & 7) << 3;

  __shared__ __align__(16) char smem[102400];
  ushort* Ks0 = (ushort*)smem;
  ushort* Ks1 = (ushort*)(smem + 16384);
  ushort* Vs0 = (ushort*)(smem + 32768);
  ushort* Vs1 = (ushort*)(smem + 49152);
  ushort* Pw  = (ushort*)(smem + 65536) + wid * (32 * 72);

  const ushort* Qb = &QKV[(size_t)b * T * RS + h * HD];
  const ushort* Kb = &QKV[(size_t)b * T * RS + 2048 + g * HD];
  const ushort* Vb = &VT[((size_t)b * G + g) * (size_t)HD * T];

#pragma unroll 1
  for (int half = 0; half < 2; half++) {
    int ch = half ? pr : (7 - pr);
    int qw = ch * 256 + wid * 32;
    int nt = 4 * (ch + 1);

    short8 qf[2][4];
#pragma unroll
    for (int mf = 0; mf < 2; mf++)
#pragma unroll
      for (int kf = 0; kf < 4; kf++)
        qf[mf][kf] = *(const short8*)&Qb[(size_t)(qw + mf * 16 + l15) * RS + kf * 32 + l4 * 8];

    f32x4 o[2][8] = {};
    float mrow[8], lrow[8];
#pragma unroll
    for (int i = 0; i < 8; i++) { mrow[i] = -3e38f; lrow[i] = 0.f; }

    stage_k8(Kb, Ks0, tid);
    stage_v8(Vb, Vs0, tid);
    __syncthreads();

#pragma unroll 1
    for (int it = 0; it < nt; ++it) {
      int t0 = it * 64;
      int cur = it & 1;
      ushort* Kc = cur ? Ks1 : Ks0;
      ushort* Vc = cur ? Vs1 : Vs0;
      if (it + 1 < nt) {
        stage_k8(Kb + (size_t)(t0 + 64) * RS, cur ? Ks0 : Ks1, tid);
        stage_v8(Vb + t0 + 64, cur ? Vs0 : Vs1, tid);
      }
      if (t0 <= qw + 31) {
        f32x4 s[2][4] = {};
#pragma unroll
        for (int kf = 0; kf < 4; kf++) {
#pragma unroll
          for (int nf = 0; nf < 4; nf++) {
            short8 bk = *(const short8*)&Kc[(nf * 16 + l15) * 128 + ((kf * 32 + l4 * 8) ^ kswz)];
            s[0][nf] = __builtin_amdgcn_mfma_f32_16x16x32_bf16(qf[0][kf], bk, s[0][nf], 0, 0, 0);
            s[1][nf] = __builtin_amdgcn_mfma_f32_16x16x32_bf16(qf[1][kf], bk, s[1][nf], 0, 0, 0);
          }
        }
        bool needmask = (t0 + 63 > qw);
#pragma unroll
        for (int mf = 0; mf < 2; mf++)
#pragma unroll
          for (int nf = 0; nf < 4; nf++)
#pragma unroll
            for (int r = 0; r < 4; r++) {
              float v = s[mf][nf][r] * SCALE2;
              if (needmask) {
                int qq = qw + mf * 16 + l4 * 4 + r;
                int kk = t0 + nf * 16 + l15;
                if (kk > qq) v = -1e30f;
              }
              s[mf][nf][r] = v;
            }
        float scs[8];
#pragma unroll
        for (int mf = 0; mf < 2; mf++)
#pragma unroll
          for (int r = 0; r < 4; r++) {
            int i = mf * 4 + r;
            float x = fmaxf(fmaxf(s[mf][0][r], s[mf][1][r]), fmaxf(s[mf][2][r], s[mf][3][r]));
            x = fmaxf(x, __shfl_xor(x, 1));
            x = fmaxf(x, __shfl_xor(x, 2));
            x = fmaxf(x, __shfl_xor(x, 4));
            x = fmaxf(x, __shfl_xor(x, 8));
            float mn = fmaxf(mrow[i], x);
            scs[i] = fexp2(mrow[i] - mn);
            mrow[i] = mn;
          }
        float rs[8];
#pragma unroll
        for (int i = 0; i < 8; i++) rs[i] = 0.f;
#pragma unroll
        for (int mf = 0; mf < 2; mf++)
#pragma unroll
          for (int nf = 0; nf < 4; nf++)
#pragma unroll
            for (int r = 0; r < 4; r++) {
              float pq = fexp2(s[mf][nf][r] - mrow[mf * 4 + r]);
              s[mf][nf][r] = pq;
              rs[mf * 4 + r] += pq;
            }
#pragma unroll
        for (int i = 0; i < 8; i++) lrow[i] = lrow[i] * scs[i] + rs[i];
#pragma unroll
        for (int mf = 0; mf < 2; mf++)
#pragma unroll
          for (int nfo = 0; nfo < 8; nfo++)
#pragma unroll
            for (int r = 0; r < 4; r++)
              o[mf][nfo][r] *= scs[mf * 4 + r];
#pragma unroll
        for (int mf = 0; mf < 2; mf++)
#pragma unroll
          for (int nf = 0; nf < 4; nf++)
#pragma unroll
            for (int r = 0; r < 4; r++)
              Pw[(mf * 16 + l4 * 4 + r) * 72 + nf * 16 + l15] = f2bf(s[mf][nf][r]);
#pragma unroll
        for (int kf = 0; kf < 2; kf++) {
          short8 pa0 = *(const short8*)&Pw[(l15) * 72 + kf * 32 + l4 * 8];
          short8 pa1 = *(const short8*)&Pw[(16 + l15) * 72 + kf * 32 + l4 * 8];
#pragma unroll
          for (int nfo = 0; nfo < 8; nfo++) {
            short8 bv = *(const short8*)&Vc[(nfo * 16 + l15) * 64 + ((kf * 32 + l4 * 8) ^ kswz)];
            o[0][nfo] = __builtin_amdgcn_mfma_f32_16x16x32_bf16(pa0, bv, o[0][nfo], 0, 0, 0);
            o[1][nfo] = __builtin_amdgcn_mfma_f32_16x16x32_bf16(pa1, bv, o[1][nfo], 0, 0, 0);
          }
        }
      }
      __syncthreads();
    }

#pragma unroll
    for (int i = 0; i < 8; i++) {
      float x = lrow[i];
      x += __shfl_xor(x, 1);
      x += __shfl_xor(x, 2);
      x += __shfl_xor(x, 4);
      x += __shfl_xor(x, 8);
      lrow[i] = x;
    }
    float inv[8];
#pragma unroll
    for (int i = 0; i < 8; i++) inv[i] = 1.0f / lrow[i];
#pragma unroll
    for (int mf = 0; mf < 2; mf++)
#pragma unroll
      for (int nfo = 0; nfo < 8; nfo++)
#pragma unroll
        for (int r = 0; r < 4; r++) {
          int t = qw + mf * 16 + l4 * 4 + r;
          int d = nfo * 16 + l15;
          O[(((size_t)b * T + t) * H + h) * HD + d] = f2bf(o[mf][nfo][r] * inv[mf * 4 + r]);
        }
    __syncthreads();
  }
}

extern "C" void kernel_launch(void* const* d_in, const int* in_sizes, int n_in,
                              void* d_out, int out_size, void* d_ws, size_t ws_size,
                              hipStream_t stream) {
  const float* x   = (const float*)d_in[0];
  const float* w_q = (const float*)d_in[1];
  const float* w_k = (const float*)d_in[2];
  const float* w_v = (const float*)d_in[3];
  const float* w_o = (const float*)d_in[4];

  char* ws = (char*)d_ws;
  ushort* xbf  = (ushort*)(ws);                // 32MB (reused as attn out)
  ushort* wkvT = (ushort*)(ws + 33554432ul);   // 12MB: [wq|wk|wv]^T = [3072,2048]
  ushort* woT  = (ushort*)(ws + 46137344ul);   // 8MB
  ushort* qkvb = (ushort*)(ws + 54525952ul);   // 48MB: (B,T,3072)
  ushort* VTb  = (ushort*)(ws + 104857600ul);  // 8MB  (total 113,246,208 B)
  ushort* attn = xbf;

  k_f32_to_bf16<<<8192, 256, 0, stream>>>(x, xbf, 16777216L);
  k_w_transpose<<<dim3(64, 64), 256, 0, stream>>>(w_q, wkvT, 2048, 2048);
  k_w_transpose<<<dim3(16, 64), 256, 0, stream>>>(w_k, wkvT + 2048ul * 2048, 2048, 512);
  k_w_transpose<<<dim3(16, 64), 256, 0, stream>>>(w_v, wkvT + 2560ul * 2048, 2048, 512);
  k_w_transpose<<<dim3(64, 64), 256, 0, stream>>>(w_o, woT, 2048, 2048);

  // merged QKV projection: 256^2 pipelined GEMM, N=3072
  k_gemm256<0><<<dim3(12, 32), 512, 0, stream>>>(xbf, wkvT, qkvb, 8192, 3072, 2048);

  k_v_transpose<<<dim3(64, 4, 16), 256, 0, stream>>>(qkvb, VTb);

  k_attn<<<256, 512, 0, stream>>>(qkvb, VTb, attn);

  k_gemm256<1><<<dim3(8, 32), 512, 0, stream>>>(attn, woT, (float*)d_out, 8192, 2048, 2048);
}

// Round 12
// 358.757 us; speedup vs baseline: 1.5675x; 1.0494x over previous
//
#include <hip/hip_runtime.h>
#include <stdint.h>

typedef __attribute__((ext_vector_type(8))) short short8;
typedef __attribute__((ext_vector_type(8))) unsigned short ushort8;
typedef __attribute__((ext_vector_type(4))) float f32x4;

__device__ __forceinline__ ushort f2bf(float f) {
  union { float f; uint32_t u; } v; v.f = f;
  uint32_t r = v.u + 0x7FFFu + ((v.u >> 16) & 1u);
  return (ushort)(r >> 16);
}

__device__ __forceinline__ ushort f2bf_trunc(float f) {  // round-to-zero, 1 op
  union { float f; uint32_t u; } v; v.f = f;
  return (ushort)(v.u >> 16);
}

__device__ __forceinline__ float fexp2(float x) {  // 2^x, single v_exp_f32
  float r;
  asm("v_exp_f32 %0, %1" : "=v"(r) : "v"(x));
  return r;
}

__device__ __forceinline__ void gld16(const ushort* g, ushort* l) {
  __builtin_amdgcn_global_load_lds((const __attribute__((address_space(1))) void*)g,
                                   (__attribute__((address_space(3))) void*)l, 16, 0, 0);
}

// ---------------- fp32 -> bf16 elementwise ----------------
__global__ __launch_bounds__(256) void k_f32_to_bf16(const float* __restrict__ in,
                                                     ushort* __restrict__ out, long n) {
  long i = ((long)blockIdx.x * 256 + threadIdx.x) * 8;
  if (i >= n) return;
  float4 a = *(const float4*)(in + i);
  float4 b = *(const float4*)(in + i + 4);
  ushort8 o;
  o[0] = f2bf(a.x); o[1] = f2bf(a.y); o[2] = f2bf(a.z); o[3] = f2bf(a.w);
  o[4] = f2bf(b.x); o[5] = f2bf(b.y); o[6] = f2bf(b.z); o[7] = f2bf(b.w);
  *(ushort8*)(out + i) = o;
}

// ---------------- fp32 (R x C) -> bf16 transposed (C x R), out row-stride R ----------------
__global__ __launch_bounds__(256) void k_w_transpose(const float* __restrict__ in,
                                                     ushort* __restrict__ out, int R, int C) {
  __shared__ float t[32][33];
  int tx = threadIdx.x & 31, ty = threadIdx.x >> 5;
  int r0 = blockIdx.y * 32, c0 = blockIdx.x * 32;
#pragma unroll
  for (int i = 0; i < 4; i++)
    t[ty + i * 8][tx] = in[(size_t)(r0 + ty + i * 8) * C + c0 + tx];
  __syncthreads();
#pragma unroll
  for (int i = 0; i < 4; i++)
    out[(size_t)(c0 + ty + i * 8) * R + r0 + tx] = f2bf(t[tx][ty + i * 8]);
}

// ---------------- V slice of QKV (B,T,3072) -> VT (B,G,HD,T) bf16 ----------------
__global__ __launch_bounds__(256) void k_v_transpose(const ushort* __restrict__ qkv,
                                                     ushort* __restrict__ out) {
  __shared__ ushort t[32][33];
  int tx = threadIdx.x & 31, ty = threadIdx.x >> 5;
  int t0 = blockIdx.x * 32, d0 = blockIdx.y * 32;
  int b = blockIdx.z >> 2, g = blockIdx.z & 3;
#pragma unroll
  for (int i = 0; i < 4; i++)
    t[ty + i * 8][tx] =
        qkv[((size_t)b * 2048 + t0 + ty + i * 8) * 3072 + 2560 + g * 128 + d0 + tx];
  __syncthreads();
#pragma unroll
  for (int i = 0; i < 4; i++)
    out[(((size_t)b * 4 + g) * 128 + d0 + ty + i * 8) * 2048 + t0 + tx] = t[tx][ty + i * 8];
}

// Stage one 256x64 bf16 tile (32KB) into LDS: 512 threads x 4 gld16.
// LDS linear [256][64]; global source col pre-XOR'd so LDS[r][c]=G[r][c^((r&7)<<3)].
__device__ __forceinline__ void stage256(const ushort* G, int ldg, ushort* Ls, int tid) {
  int l = tid & 63, w = tid >> 6;
  int rsub = l >> 3;
  int cs = ((l & 7) ^ rsub) << 3;
#pragma unroll
  for (int n = 0; n < 4; n++) {
    int c = n * 8 + w;
    gld16(G + (size_t)(c * 8 + rsub) * ldg + cs, Ls + c * 512 + l * 8);
  }
}

// ---------------- 256x256 GEMM, BK=64, counted-vmcnt double-buffer pipeline ------
// (unchanged from round 11 — verified)
template <int F32OUT>
__global__ __launch_bounds__(512) void k_gemm256(const ushort* __restrict__ A,
                                                 const ushort* __restrict__ BT,
                                                 void* __restrict__ C, int M, int N, int K) {
  __shared__ ushort As0[256 * 64], As1[256 * 64];
  __shared__ ushort Bs0[256 * 64], Bs1[256 * 64];
  const int tid = threadIdx.x;
  const int lane = tid & 63, wid = tid >> 6;
  const int wm = wid >> 2, wn = wid & 3;
  const int l15 = lane & 15, l4 = lane >> 4;
  const int rsw = (l15 & 7) << 3;
  int nwg = gridDim.x * gridDim.y;
  int lin = blockIdx.y * gridDim.x + blockIdx.x;
  int swz = (lin & 7) * (nwg >> 3) + (lin >> 3);
  int bx = swz % gridDim.x, by = swz / gridDim.x;
  const int m0 = by * 256, n0 = bx * 256;

  const ushort* Atile = A + (size_t)m0 * K;
  const ushort* Btile = BT + (size_t)n0 * K;
  const int NK = K >> 6;

  f32x4 acc[8][4] = {};

  stage256(Atile, K, As0, tid);
  stage256(Btile, K, Bs0, tid);
  stage256(Atile + 64, K, As1, tid);
  stage256(Btile + 64, K, Bs1, tid);
  asm volatile("s_waitcnt vmcnt(8)" ::: "memory");
  asm volatile("s_barrier" ::: "memory");

  for (int kt = 0; kt < NK; ++kt) {
    const ushort* Ab = (kt & 1) ? As1 : As0;
    const ushort* Bb = (kt & 1) ? Bs1 : Bs0;
    short8 bfrag[4][2];
#pragma unroll
    for (int nf = 0; nf < 4; nf++)
#pragma unroll
      for (int ks = 0; ks < 2; ks++)
        bfrag[nf][ks] = *(const short8*)&Bb[(wn * 64 + nf * 16 + l15) * 64 +
                                            ((ks * 32 + l4 * 8) ^ rsw)];
#pragma unroll
    for (int q = 0; q < 4; q++) {
      short8 afr[2][2];
#pragma unroll
      for (int dm = 0; dm < 2; dm++)
#pragma unroll
        for (int ks = 0; ks < 2; ks++)
          afr[dm][ks] = *(const short8*)&Ab[(wm * 128 + (q * 2 + dm) * 16 + l15) * 64 +
                                            ((ks * 32 + l4 * 8) ^ rsw)];
      __builtin_amdgcn_s_setprio(1);
#pragma unroll
      for (int dm = 0; dm < 2; dm++)
#pragma unroll
        for (int nf = 0; nf < 4; nf++)
#pragma unroll
          for (int ks = 0; ks < 2; ks++)
            acc[q * 2 + dm][nf] = __builtin_amdgcn_mfma_f32_16x16x32_bf16(
                afr[dm][ks], bfrag[nf][ks], acc[q * 2 + dm][nf], 0, 0, 0);
      __builtin_amdgcn_s_setprio(0);
    }
    asm volatile("s_barrier" ::: "memory");
    if (kt + 2 < NK) {
      stage256(Atile + (kt + 2) * 64, K, (kt & 1) ? As1 : As0, tid);
      stage256(Btile + (kt + 2) * 64, K, (kt & 1) ? Bs1 : Bs0, tid);
      asm volatile("s_waitcnt vmcnt(8)" ::: "memory");
    } else {
      asm volatile("s_waitcnt vmcnt(0)" ::: "memory");
    }
    asm volatile("s_barrier" ::: "memory");
  }

#pragma unroll
  for (int mf = 0; mf < 8; mf++)
#pragma unroll
    for (int nf = 0; nf < 4; nf++)
#pragma unroll
      for (int r = 0; r < 4; r++) {
        int m = m0 + wm * 128 + mf * 16 + l4 * 4 + r;
        int n = n0 + wn * 64 + nf * 16 + l15;
        if (F32OUT)
          ((float*)C)[(size_t)m * N + n] = acc[mf][nf][r];
        else
          ((ushort*)C)[(size_t)m * N + n] = f2bf(acc[mf][nf][r]);
      }
}

// K tile stage (shared across 8 waves, 2 DMA lines per thread)
__device__ __forceinline__ void stage_k8(const ushort* Kt, ushort* Ks, int tid) {
  int l = tid & 63, w = tid >> 6;
#pragma unroll
  for (int n = 0; n < 2; n++) {
    int cidx = w * 2 + n;
    int r = cidx * 4 + (l >> 4);
    int cs = ((l & 15) * 8) ^ ((r & 7) << 3);
    gld16(Kt + (size_t)r * 3072 + cs, Ks + cidx * 512 + l * 8);
  }
}

__device__ __forceinline__ void stage_v8(const ushort* Vt, ushort* Vs, int tid) {
  int l = tid & 63, w = tid >> 6;
#pragma unroll
  for (int n = 0; n < 2; n++) {
    int cidx = w * 2 + n;
    int d = cidx * 8 + (l >> 3);
    int cs = ((l & 7) * 8) ^ ((d & 7) << 3);
    gld16(Vt + (size_t)d * 2048 + cs, Vs + cidx * 512 + l * 8);
  }
}

// ---------------- causal GQA flash attention: 8-wave blocks, shared K/V LDS ------
// R10 structure (verified 150.8us) + round-12 VALU diet:
//  - raw scores kept; p = exp2(fma(raw,SCALE2,-m)) (fused scale, no separate pass)
//  - T13 defer-max: o-rescale/m-update only when tile max grows past THR=11.5
//    (log2 domain); VGPR headroom free since occupancy is LDS-bound (1 blk/CU)
//  - P staged to LDS with 1-op truncating bf16 pack
__global__ __launch_bounds__(512) void k_attn(const ushort* __restrict__ QKV,
                                              const ushort* __restrict__ VT,
                                              ushort* __restrict__ O) {
  const int T = 2048, HD = 128, G = 4, H = 16, RS = 3072;
  const float SCALE2 = 0.08838834764831845f * 1.4426950408889634f;
  int bid = blockIdx.x;
  int pr = bid >> 6;
  int bh = bid & 63;
  int h = bh & 15, b = bh >> 4;
  int g = h & 3;
  int tid = threadIdx.x, wid = tid >> 6, lane = tid & 63;
  int l15 = lane & 15, l4 = lane >> 4;
  int kswz = (l15 & 7) << 3;

  __shared__ __align__(16) char smem[102400];
  ushort* Ks0 = (ushort*)smem;
  ushort* Ks1 = (ushort*)(smem + 16384);
  ushort* Vs0 = (ushort*)(smem + 32768);
  ushort* Vs1 = (ushort*)(smem + 49152);
  ushort* Pw  = (ushort*)(smem + 65536) + wid * (32 * 72);

  const ushort* Qb = &QKV[(size_t)b * T * RS + h * HD];
  const ushort* Kb = &QKV[(size_t)b * T * RS + 2048 + g * HD];
  const ushort* Vb = &VT[((size_t)b * G + g) * (size_t)HD * T];

#pragma unroll 1
  for (int half = 0; half < 2; half++) {
    int ch = half ? pr : (7 - pr);
    int qw = ch * 256 + wid * 32;
    int nt = 4 * (ch + 1);

    short8 qf[2][4];
#pragma unroll
    for (int mf = 0; mf < 2; mf++)
#pragma unroll
      for (int kf = 0; kf < 4; kf++)
        qf[mf][kf] = *(const short8*)&Qb[(size_t)(qw + mf * 16 + l15) * RS + kf * 32 + l4 * 8];

    f32x4 o[2][8] = {};
    float mrow[8], lrow[8];
#pragma unroll
    for (int i = 0; i < 8; i++) { mrow[i] = -3e38f; lrow[i] = 0.f; }

    stage_k8(Kb, Ks0, tid);
    stage_v8(Vb, Vs0, tid);
    __syncthreads();

#pragma unroll 1
    for (int it = 0; it < nt; ++it) {
      int t0 = it * 64;
      int cur = it & 1;
      ushort* Kc = cur ? Ks1 : Ks0;
      ushort* Vc = cur ? Vs1 : Vs0;
      if (it + 1 < nt) {
        stage_k8(Kb + (size_t)(t0 + 64) * RS, cur ? Ks0 : Ks1, tid);
        stage_v8(Vb + t0 + 64, cur ? Vs0 : Vs1, tid);
      }
      if (t0 <= qw + 31) {
        f32x4 s[2][4] = {};  // raw (unscaled) scores
#pragma unroll
        for (int kf = 0; kf < 4; kf++) {
#pragma unroll
          for (int nf = 0; nf < 4; nf++) {
            short8 bk = *(const short8*)&Kc[(nf * 16 + l15) * 128 + ((kf * 32 + l4 * 8) ^ kswz)];
            s[0][nf] = __builtin_amdgcn_mfma_f32_16x16x32_bf16(qf[0][kf], bk, s[0][nf], 0, 0, 0);
            s[1][nf] = __builtin_amdgcn_mfma_f32_16x16x32_bf16(qf[1][kf], bk, s[1][nf], 0, 0, 0);
          }
        }
        bool needmask = (t0 + 63 > qw);
        if (needmask) {
#pragma unroll
          for (int mf = 0; mf < 2; mf++)
#pragma unroll
            for (int nf = 0; nf < 4; nf++)
#pragma unroll
              for (int r = 0; r < 4; r++) {
                int qq = qw + mf * 16 + l4 * 4 + r;
                int kk = t0 + nf * 16 + l15;
                if (kk > qq) s[mf][nf][r] = -1e30f;
              }
        }
        // tile row-max (raw) -> scaled; T13 defer-max decision
        float xs8[8];
        bool ok = true;
#pragma unroll
        for (int mf = 0; mf < 2; mf++)
#pragma unroll
          for (int r = 0; r < 4; r++) {
            int i = mf * 4 + r;
            float x = fmaxf(fmaxf(s[mf][0][r], s[mf][1][r]), fmaxf(s[mf][2][r], s[mf][3][r]));
            x = fmaxf(x, __shfl_xor(x, 1));
            x = fmaxf(x, __shfl_xor(x, 2));
            x = fmaxf(x, __shfl_xor(x, 4));
            x = fmaxf(x, __shfl_xor(x, 8));
            float xs = x * SCALE2;
            xs8[i] = xs;
            ok = ok && (xs <= mrow[i] + 11.5f);
          }
        if (!__all(ok)) {  // rescale only when max grew past threshold
#pragma unroll
          for (int i = 0; i < 8; i++) {
            float mn = fmaxf(mrow[i], xs8[i]);
            float sc = fexp2(mrow[i] - mn);
            mrow[i] = mn;
            lrow[i] *= sc;
#pragma unroll
            for (int nfo = 0; nfo < 8; nfo++)
              o[i >> 2][nfo][i & 3] *= sc;
          }
        }
        // p = 2^(raw*SCALE2 - m); per-lane partial sums; truncating bf16 store
        float rs[8];
#pragma unroll
        for (int i = 0; i < 8; i++) rs[i] = 0.f;
#pragma unroll
        for (int mf = 0; mf < 2; mf++)
#pragma unroll
          for (int nf = 0; nf < 4; nf++)
#pragma unroll
            for (int r = 0; r < 4; r++) {
              float pq = fexp2(__builtin_fmaf(s[mf][nf][r], SCALE2, -mrow[mf * 4 + r]));
              rs[mf * 4 + r] += pq;
              Pw[(mf * 16 + l4 * 4 + r) * 72 + nf * 16 + l15] = f2bf_trunc(pq);
            }
#pragma unroll
        for (int i = 0; i < 8; i++) lrow[i] += rs[i];
#pragma unroll
        for (int kf = 0; kf < 2; kf++) {
          short8 pa0 = *(const short8*)&Pw[(l15) * 72 + kf * 32 + l4 * 8];
          short8 pa1 = *(const short8*)&Pw[(16 + l15) * 72 + kf * 32 + l4 * 8];
#pragma unroll
          for (int nfo = 0; nfo < 8; nfo++) {
            short8 bv = *(const short8*)&Vc[(nfo * 16 + l15) * 64 + ((kf * 32 + l4 * 8) ^ kswz)];
            o[0][nfo] = __builtin_amdgcn_mfma_f32_16x16x32_bf16(pa0, bv, o[0][nfo], 0, 0, 0);
            o[1][nfo] = __builtin_amdgcn_mfma_f32_16x16x32_bf16(pa1, bv, o[1][nfo], 0, 0, 0);
          }
        }
      }
      __syncthreads();
    }

#pragma unroll
    for (int i = 0; i < 8; i++) {
      float x = lrow[i];
      x += __shfl_xor(x, 1);
      x += __shfl_xor(x, 2);
      x += __shfl_xor(x, 4);
      x += __shfl_xor(x, 8);
      lrow[i] = x;
    }
    float inv[8];
#pragma unroll
    for (int i = 0; i < 8; i++) inv[i] = 1.0f / lrow[i];
#pragma unroll
    for (int mf = 0; mf < 2; mf++)
#pragma unroll
      for (int nfo = 0; nfo < 8; nfo++)
#pragma unroll
        for (int r = 0; r < 4; r++) {
          int t = qw + mf * 16 + l4 * 4 + r;
          int d = nfo * 16 + l15;
          O[(((size_t)b * T + t) * H + h) * HD + d] = f2bf(o[mf][nfo][r] * inv[mf * 4 + r]);
        }
    __syncthreads();
  }
}

extern "C" void kernel_launch(void* const* d_in, const int* in_sizes, int n_in,
                              void* d_out, int out_size, void* d_ws, size_t ws_size,
                              hipStream_t stream) {
  const float* x   = (const float*)d_in[0];
  const float* w_q = (const float*)d_in[1];
  const float* w_k = (const float*)d_in[2];
  const float* w_v = (const float*)d_in[3];
  const float* w_o = (const float*)d_in[4];

  char* ws = (char*)d_ws;
  ushort* xbf  = (ushort*)(ws);                // 32MB (reused as attn out)
  ushort* wkvT = (ushort*)(ws + 33554432ul);   // 12MB: [wq|wk|wv]^T = [3072,2048]
  ushort* woT  = (ushort*)(ws + 46137344ul);   // 8MB
  ushort* qkvb = (ushort*)(ws + 54525952ul);   // 48MB: (B,T,3072)
  ushort* VTb  = (ushort*)(ws + 104857600ul);  // 8MB  (total 113,246,208 B)
  ushort* attn = xbf;

  k_f32_to_bf16<<<8192, 256, 0, stream>>>(x, xbf, 16777216L);
  k_w_transpose<<<dim3(64, 64), 256, 0, stream>>>(w_q, wkvT, 2048, 2048);
  k_w_transpose<<<dim3(16, 64), 256, 0, stream>>>(w_k, wkvT + 2048ul * 2048, 2048, 512);
  k_w_transpose<<<dim3(16, 64), 256, 0, stream>>>(w_v, wkvT + 2560ul * 2048, 2048, 512);
  k_w_transpose<<<dim3(64, 64), 256, 0, stream>>>(w_o, woT, 2048, 2048);

  k_gemm256<0><<<dim3(12, 32), 512, 0, stream>>>(xbf, wkvT, qkvb, 8192, 3072, 2048);

  k_v_transpose<<<dim3(64, 4, 16), 256, 0, stream>>>(qkvb, VTb);

  k_attn<<<256, 512, 0, stream>>>(qkvb, VTb, attn);

  k_gemm256<1><<<dim3(8, 32), 512, 0, stream>>>(attn, woT, (float*)d_out, 8192, 2048, 2048);
}